// Round 1
// baseline (348.138 us; speedup 1.0000x reference)
//
#include <hip/hip_runtime.h>
#include <hip/hip_bf16.h>

// Shapes (fixed by the reference)
#define BB 32          // batch
#define CC 1024        // channels
#define HH 18
#define WW 32
#define HWSZ 576       // H*W
#define KCTX 8         // CONTEXT_LEN
#define TT 9           // K+1
#define NH 8
#define HD 128

// ---------------------------------------------------------------------------
// K1: spatial mean pooling -> context [B][T][C]
// One wave (64 lanes) per output row; each row = 576 contiguous floats.
// ---------------------------------------------------------------------------
__global__ __launch_bounds__(256) void pool_kernel(
    const float* __restrict__ hbuf,   // [K][B][C][H][W]
    const float* __restrict__ hcur,   // [B][C][H][W]
    float* __restrict__ ctx)          // [B][T][C]
{
    const int wave = threadIdx.x >> 6;
    const int lane = threadIdx.x & 63;
    const int r = blockIdx.x * 4 + wave;          // 0 .. B*T*C-1 = 294911
    const int b = r / (TT * CC);
    const int rem = r - b * (TT * CC);
    const int t = rem >> 10;                      // / C
    const int c = rem & (CC - 1);

    const float* src = (t < KCTX)
        ? (hbuf + (size_t)((t * BB + b) * CC + c) * HWSZ)
        : (hcur + (size_t)(b * CC + c) * HWSZ);

    const float4* s4 = (const float4*)src;        // 144 float4 per row
    float4 v0 = s4[lane];
    float4 v1 = s4[lane + 64];
    float sum = v0.x + v0.y + v0.z + v0.w + v1.x + v1.y + v1.z + v1.w;
    if (lane < 16) {
        float4 v2 = s4[lane + 128];
        sum += v2.x + v2.y + v2.z + v2.w;
    }
#pragma unroll
    for (int off = 32; off; off >>= 1) sum += __shfl_xor(sum, off);
    if (lane == 0) ctx[r] = sum * (1.0f / 576.0f);
}

// ---------------------------------------------------------------------------
// Generic fp32 GEMM: Y[M][N] = A[M][K] @ B[N][K]^T (+ bias[N])
// K fixed = 1024. Tile: BM=32 x BN=128, BK=32, 256 threads, thread-tile 2x8.
// ---------------------------------------------------------------------------
#define GBM 32
#define GBN 128
#define GBK 32
#define GK  1024

__global__ __launch_bounds__(256) void gemm_abt(
    const float* __restrict__ A, int lda,
    const float* __restrict__ B, int ldb,
    const float* __restrict__ bias,
    float* __restrict__ Y, int ldy,
    int ntiles_n)
{
    __shared__ float As[GBM][GBK + 4];        // k-contiguous rows
    __shared__ float Bs[GBK][GBN + 4];        // transposed: [k][n]

    const int bid = blockIdx.x;
    const int bm = bid / ntiles_n;
    const int bn = bid - bm * ntiles_n;
    const int tid = threadIdx.x;
    const int tx = tid & 15;                  // 0..15 -> col group (8 cols)
    const int ty = tid >> 4;                  // 0..15 -> row group (2 rows)

    const float* Ablk = A + (size_t)bm * GBM * lda;
    const float* Bblk = B + (size_t)bn * GBN * ldb;

    float acc0[8], acc1[8];
#pragma unroll
    for (int i = 0; i < 8; ++i) { acc0[i] = 0.f; acc1[i] = 0.f; }

    for (int kt = 0; kt < GK; kt += GBK) {
        // stage A: 32 rows x 32 k = 256 float4; one per thread
        {
            const int row = tid >> 3;
            const int kc = (tid & 7) << 2;
            float4 a = *(const float4*)(Ablk + (size_t)row * lda + kt + kc);
            *(float4*)(&As[row][kc]) = a;     // (BK+4)=36 -> 16B aligned
        }
        // stage B transposed: 128 rows x 32 k = 1024 float4; four per thread
        {
            const int kc = (tid & 7) << 2;
            const int r0 = tid >> 3;
#pragma unroll
            for (int rr = 0; rr < 4; ++rr) {
                const int row = r0 + rr * 32;
                float4 bv = *(const float4*)(Bblk + (size_t)row * ldb + kt + kc);
                Bs[kc + 0][row] = bv.x;
                Bs[kc + 1][row] = bv.y;
                Bs[kc + 2][row] = bv.z;
                Bs[kc + 3][row] = bv.w;
            }
        }
        __syncthreads();

#pragma unroll
        for (int k4 = 0; k4 < GBK; k4 += 4) {
            float4 a0 = *(const float4*)(&As[ty * 2 + 0][k4]);
            float4 a1 = *(const float4*)(&As[ty * 2 + 1][k4]);
            const float a0v[4] = {a0.x, a0.y, a0.z, a0.w};
            const float a1v[4] = {a1.x, a1.y, a1.z, a1.w};
#pragma unroll
            for (int i = 0; i < 4; ++i) {
                float4 blo = *(const float4*)(&Bs[k4 + i][tx * 8]);
                float4 bhi = *(const float4*)(&Bs[k4 + i][tx * 8 + 4]);
                acc0[0] += a0v[i] * blo.x;  acc0[1] += a0v[i] * blo.y;
                acc0[2] += a0v[i] * blo.z;  acc0[3] += a0v[i] * blo.w;
                acc0[4] += a0v[i] * bhi.x;  acc0[5] += a0v[i] * bhi.y;
                acc0[6] += a0v[i] * bhi.z;  acc0[7] += a0v[i] * bhi.w;
                acc1[0] += a1v[i] * blo.x;  acc1[1] += a1v[i] * blo.y;
                acc1[2] += a1v[i] * blo.z;  acc1[3] += a1v[i] * blo.w;
                acc1[4] += a1v[i] * bhi.x;  acc1[5] += a1v[i] * bhi.y;
                acc1[6] += a1v[i] * bhi.z;  acc1[7] += a1v[i] * bhi.w;
            }
        }
        __syncthreads();
    }

    // epilogue
    const int col = bn * GBN + tx * 8;
    float bv[8];
#pragma unroll
    for (int i = 0; i < 8; ++i) bv[i] = bias ? bias[col + i] : 0.f;

    const int row0 = bm * GBM + ty * 2;
    float* y0 = Y + (size_t)row0 * ldy + col;
    float* y1 = y0 + ldy;
    float4 w;
    w = make_float4(acc0[0] + bv[0], acc0[1] + bv[1], acc0[2] + bv[2], acc0[3] + bv[3]);
    *(float4*)(y0 + 0) = w;
    w = make_float4(acc0[4] + bv[4], acc0[5] + bv[5], acc0[6] + bv[6], acc0[7] + bv[7]);
    *(float4*)(y0 + 4) = w;
    w = make_float4(acc1[0] + bv[0], acc1[1] + bv[1], acc1[2] + bv[2], acc1[3] + bv[3]);
    *(float4*)(y1 + 0) = w;
    w = make_float4(acc1[4] + bv[4], acc1[5] + bv[5], acc1[6] + bv[6], acc1[7] + bv[7]);
    *(float4*)(y1 + 4) = w;
}

// ---------------------------------------------------------------------------
// K3: attention for the LAST query only (causal mask is a no-op on last row).
// One wave per (b, h) pair. kv layout: [B*T][2048] = [k(1024) | v(1024)]
// ---------------------------------------------------------------------------
__global__ __launch_bounds__(256) void attn_kernel(
    const float* __restrict__ kv,
    const float* __restrict__ q,        // [B][C] (last-timestep Q)
    const float* __restrict__ rel_emb,  // [17][8]
    float* __restrict__ attn_out)       // [B][C]
{
    const int wave = threadIdx.x >> 6;
    const int lane = threadIdx.x & 63;
    const int pair = blockIdx.x * 4 + wave;   // 0..255
    const int b = pair >> 3;
    const int h = pair & 7;
    const float scale = 0.08838834764831845f; // 1/sqrt(128)

    const float* qb = q + b * CC + h * HD;
    const float q1 = qb[lane] * scale;
    const float q2 = qb[lane + 64] * scale;

    float s[TT];
#pragma unroll
    for (int j = 0; j < TT; ++j) {
        const float* kb = kv + (size_t)(b * TT + j) * 2048 + h * HD;
        float p = q1 * kb[lane] + q2 * kb[lane + 64];
#pragma unroll
        for (int off = 32; off; off >>= 1) p += __shfl_xor(p, off);
        s[j] = p + rel_emb[(2 * KCTX - j) * NH + h];  // bias row q=T-1
    }
    float m = s[0];
#pragma unroll
    for (int j = 1; j < TT; ++j) m = fmaxf(m, s[j]);
    float sum = 0.f;
#pragma unroll
    for (int j = 0; j < TT; ++j) { s[j] = expf(s[j] - m); sum += s[j]; }
    const float inv = 1.0f / sum;

    float a1 = 0.f, a2 = 0.f;
#pragma unroll
    for (int j = 0; j < TT; ++j) {
        const float* vb = kv + (size_t)(b * TT + j) * 2048 + 1024 + h * HD;
        a1 += s[j] * vb[lane];
        a2 += s[j] * vb[lane + 64];
    }
    attn_out[b * CC + h * HD + lane] = a1 * inv;
    attn_out[b * CC + h * HD + lane + 64] = a2 * inv;
}

// ---------------------------------------------------------------------------
// K5: y = h_current + out[b][c] broadcast over spatial dims
// ---------------------------------------------------------------------------
__global__ __launch_bounds__(256) void final_add(
    const float* __restrict__ hc,
    const float* __restrict__ out,      // [B][C]
    float* __restrict__ y, int n4)
{
    int i = blockIdx.x * blockDim.x + threadIdx.x;
    const int stride = gridDim.x * blockDim.x;
    for (; i < n4; i += stride) {
        float4 v = ((const float4*)hc)[i];
        const float add = out[i / 144];       // 4 floats / (576 per channel)
        v.x += add; v.y += add; v.z += add; v.w += add;
        ((float4*)y)[i] = v;
    }
}

// ---------------------------------------------------------------------------
extern "C" void kernel_launch(void* const* d_in, const int* in_sizes, int n_in,
                              void* d_out, int out_size, void* d_ws, size_t ws_size,
                              hipStream_t stream) {
    const float* h_current = (const float*)d_in[0];  // [32,1024,18,32]
    const float* h_buffer  = (const float*)d_in[1];  // [8,32,1024,18,32]
    const float* W_qkv     = (const float*)d_in[2];  // [3072,1024]
    const float* W_out     = (const float*)d_in[3];  // [1024,1024]
    const float* b_out     = (const float*)d_in[4];  // [1024]
    const float* rel_emb   = (const float*)d_in[5];  // [17,8]

    float* ws = (float*)d_ws;
    float* ctx  = ws;                        // [288][1024]   = 294912
    float* kvb  = ws + 294912;               // [288][2048]   = 589824
    float* qb   = ws + 884736;               // [32][1024]    = 32768
    float* attn = ws + 917504;               // [32][1024]    = 32768
    float* outp = ws + 950272;               // [32][1024]    = 32768

    // K1: pooling. B*T*C rows, 4 rows per block.
    pool_kernel<<<(BB * TT * CC) / 4, 256, 0, stream>>>(h_buffer, h_current, ctx);

    // K2a: KV = context @ W_kv^T   (M=288, N=2048)
    gemm_abt<<<(288 / GBM) * (2048 / GBN), 256, 0, stream>>>(
        ctx, CC, W_qkv + (size_t)1024 * 1024, 1024, nullptr, kvb, 2048, 2048 / GBN);

    // K2b: Q_last = context[:, 8, :] @ W_q^T  (M=32, N=1024)
    gemm_abt<<<(32 / GBM) * (1024 / GBN), 256, 0, stream>>>(
        ctx + 8 * CC, TT * CC, W_qkv, 1024, nullptr, qb, 1024, 1024 / GBN);

    // K3: attention (last query), one wave per (b,h)
    attn_kernel<<<(BB * NH) / 4, 256, 0, stream>>>(kvb, qb, rel_emb, attn);

    // K4: out = attn @ W_out^T + b_out  (M=32, N=1024)
    gemm_abt<<<(32 / GBM) * (1024 / GBN), 256, 0, stream>>>(
        attn, CC, W_out, 1024, b_out, outp, 1024, 1024 / GBN);

    // K5: y = h_current + out broadcast
    const int n4 = (BB * CC * HWSZ) / 4;     // 4,718,592
    final_add<<<2048, 256, 0, stream>>>(h_current, outp, (float*)d_out, n4);
}

// Round 2
// 212.520 us; speedup vs baseline: 1.6381x; 1.6381x over previous
//
#include <hip/hip_runtime.h>
#include <hip/hip_bf16.h>

// Shapes (fixed by the reference)
#define BB 32          // batch
#define CC 1024        // channels
#define HH 18
#define WW 32
#define HWSZ 576       // H*W
#define KCTX 8         // CONTEXT_LEN
#define TT 9           // K+1
#define NH 8
#define HD 128

// ---------------------------------------------------------------------------
// K1: spatial mean pooling -> context [B][T][C]
// One wave per row (576 contiguous floats). Buffer rows first in memory
// order (streams 604 MB), h_current rows LAST so its 75.5 MB stays L3-hot
// for final_add's re-read.
// ---------------------------------------------------------------------------
__global__ __launch_bounds__(256) void pool_kernel(
    const float* __restrict__ hbuf,   // [K][B][C][H][W]
    const float* __restrict__ hcur,   // [B][C][H][W]
    float* __restrict__ ctx)          // [B][T][C]
{
    const int wave = threadIdx.x >> 6;
    const int lane = threadIdx.x & 63;
    const int r = blockIdx.x * 4 + wave;          // 0 .. 294911

    const float* src;
    int cidx;
    if (r < KCTX * BB * CC) {                     // buffer rows, memory order
        src = hbuf + (size_t)r * HWSZ;
        const int t = r >> 15;                    // / (B*C)
        const int b = (r >> 10) & 31;
        const int c = r & (CC - 1);
        cidx = (b * TT + t) * CC + c;
    } else {                                      // current rows, last
        const int rc = r - KCTX * BB * CC;
        src = hcur + (size_t)rc * HWSZ;
        const int b = rc >> 10;
        const int c = rc & (CC - 1);
        cidx = (b * TT + KCTX) * CC + c;
    }

    const float4* s4 = (const float4*)src;        // 144 float4 per row
    float4 v0 = s4[lane];
    float4 v1 = s4[lane + 64];
    float sum = v0.x + v0.y + v0.z + v0.w + v1.x + v1.y + v1.z + v1.w;
    if (lane < 16) {
        float4 v2 = s4[lane + 128];
        sum += v2.x + v2.y + v2.z + v2.w;
    }
#pragma unroll
    for (int off = 32; off; off >>= 1) sum += __shfl_xor(sum, off);
    if (lane == 0) ctx[cidx] = sum * (1.0f / 576.0f);
}

// ---------------------------------------------------------------------------
// Split-K fp32 GEMM: Ypart[s][M][N] = A[M][K-slice s] @ B[N][K-slice s]^T
// K=1024 total, 8 splits x 128. Tile 32x128, BK=32, 256 thr, thread-tile 2x8.
// ---------------------------------------------------------------------------
#define GBM 32
#define GBN 128
#define GBK 32
#define SKLEN 128      // K per split
#define NSPLIT 8

__global__ __launch_bounds__(256) void gemm_splitk(
    const float* __restrict__ A, int lda,
    const float* __restrict__ B, int ldb,
    float* __restrict__ Ypart, int ldy, int mn,
    int ntiles_n)
{
    __shared__ float As[GBM][GBK + 4];
    __shared__ float Bs[GBK][GBN + 4];

    const int bid = blockIdx.x;
    const int s = blockIdx.y;
    const int bm = bid / ntiles_n;
    const int bn = bid - bm * ntiles_n;
    const int tid = threadIdx.x;
    const int tx = tid & 15;
    const int ty = tid >> 4;

    const float* Ablk = A + (size_t)bm * GBM * lda;
    const float* Bblk = B + (size_t)bn * GBN * ldb;
    const int k0 = s * SKLEN;

    float acc0[8], acc1[8];
#pragma unroll
    for (int i = 0; i < 8; ++i) { acc0[i] = 0.f; acc1[i] = 0.f; }

    for (int kt = k0; kt < k0 + SKLEN; kt += GBK) {
        {
            const int row = tid >> 3;
            const int kc = (tid & 7) << 2;
            float4 a = *(const float4*)(Ablk + (size_t)row * lda + kt + kc);
            *(float4*)(&As[row][kc]) = a;
        }
        {
            const int kc = (tid & 7) << 2;
            const int r0 = tid >> 3;
#pragma unroll
            for (int rr = 0; rr < 4; ++rr) {
                const int row = r0 + rr * 32;
                float4 bv = *(const float4*)(Bblk + (size_t)row * ldb + kt + kc);
                Bs[kc + 0][row] = bv.x;
                Bs[kc + 1][row] = bv.y;
                Bs[kc + 2][row] = bv.z;
                Bs[kc + 3][row] = bv.w;
            }
        }
        __syncthreads();

#pragma unroll
        for (int k4 = 0; k4 < GBK; k4 += 4) {
            float4 a0 = *(const float4*)(&As[ty * 2 + 0][k4]);
            float4 a1 = *(const float4*)(&As[ty * 2 + 1][k4]);
            const float a0v[4] = {a0.x, a0.y, a0.z, a0.w};
            const float a1v[4] = {a1.x, a1.y, a1.z, a1.w};
#pragma unroll
            for (int i = 0; i < 4; ++i) {
                float4 blo = *(const float4*)(&Bs[k4 + i][tx * 8]);
                float4 bhi = *(const float4*)(&Bs[k4 + i][tx * 8 + 4]);
                acc0[0] += a0v[i] * blo.x;  acc0[1] += a0v[i] * blo.y;
                acc0[2] += a0v[i] * blo.z;  acc0[3] += a0v[i] * blo.w;
                acc0[4] += a0v[i] * bhi.x;  acc0[5] += a0v[i] * bhi.y;
                acc0[6] += a0v[i] * bhi.z;  acc0[7] += a0v[i] * bhi.w;
                acc1[0] += a1v[i] * blo.x;  acc1[1] += a1v[i] * blo.y;
                acc1[2] += a1v[i] * blo.z;  acc1[3] += a1v[i] * blo.w;
                acc1[4] += a1v[i] * bhi.x;  acc1[5] += a1v[i] * bhi.y;
                acc1[6] += a1v[i] * bhi.z;  acc1[7] += a1v[i] * bhi.w;
            }
        }
        __syncthreads();
    }

    float* Y = Ypart + (size_t)s * mn;
    const int col = bn * GBN + tx * 8;
    const int row0 = bm * GBM + ty * 2;
    float* y0 = Y + (size_t)row0 * ldy + col;
    float* y1 = y0 + ldy;
    *(float4*)(y0 + 0) = make_float4(acc0[0], acc0[1], acc0[2], acc0[3]);
    *(float4*)(y0 + 4) = make_float4(acc0[4], acc0[5], acc0[6], acc0[7]);
    *(float4*)(y1 + 0) = make_float4(acc1[0], acc1[1], acc1[2], acc1[3]);
    *(float4*)(y1 + 4) = make_float4(acc1[4], acc1[5], acc1[6], acc1[7]);
}

// ---------------------------------------------------------------------------
// Reduce S partial slabs (+ optional bias). nmask = N-1 (N power of 2).
// ---------------------------------------------------------------------------
__global__ __launch_bounds__(256) void reduce_splitk(
    const float* __restrict__ part,
    const float* __restrict__ bias,
    float* __restrict__ Y, int mn, int nmask)
{
    const int i = blockIdx.x * 256 + threadIdx.x;   // float4 index
    if (i >= (mn >> 2)) return;
    float4 acc = ((const float4*)part)[i];
#pragma unroll
    for (int s = 1; s < NSPLIT; ++s) {
        float4 v = ((const float4*)(part + (size_t)s * mn))[i];
        acc.x += v.x; acc.y += v.y; acc.z += v.z; acc.w += v.w;
    }
    if (bias) {
        const int col = (i << 2) & nmask;
        float4 bv = *(const float4*)(bias + col);
        acc.x += bv.x; acc.y += bv.y; acc.z += bv.z; acc.w += bv.w;
    }
    ((float4*)Y)[i] = acc;
}

// ---------------------------------------------------------------------------
// K3: attention for the LAST query only (causal mask no-op on last row).
// One wave per (b, h). kv layout: [B*T][2048] = [k(1024) | v(1024)]
// ---------------------------------------------------------------------------
__global__ __launch_bounds__(256) void attn_kernel(
    const float* __restrict__ kv,
    const float* __restrict__ q,        // [B][C]
    const float* __restrict__ rel_emb,  // [17][8]
    float* __restrict__ attn_out)       // [B][C]
{
    const int wave = threadIdx.x >> 6;
    const int lane = threadIdx.x & 63;
    const int pair = blockIdx.x * 4 + wave;   // 0..255
    const int b = pair >> 3;
    const int h = pair & 7;
    const float scale = 0.08838834764831845f; // 1/sqrt(128)

    const float* qb = q + b * CC + h * HD;
    const float q1 = qb[lane] * scale;
    const float q2 = qb[lane + 64] * scale;

    float s[TT];
#pragma unroll
    for (int j = 0; j < TT; ++j) {
        const float* kb = kv + (size_t)(b * TT + j) * 2048 + h * HD;
        float p = q1 * kb[lane] + q2 * kb[lane + 64];
#pragma unroll
        for (int off = 32; off; off >>= 1) p += __shfl_xor(p, off);
        s[j] = p + rel_emb[(2 * KCTX - j) * NH + h];
    }
    float m = s[0];
#pragma unroll
    for (int j = 1; j < TT; ++j) m = fmaxf(m, s[j]);
    float sum = 0.f;
#pragma unroll
    for (int j = 0; j < TT; ++j) { s[j] = expf(s[j] - m); sum += s[j]; }
    const float inv = 1.0f / sum;

    float a1 = 0.f, a2 = 0.f;
#pragma unroll
    for (int j = 0; j < TT; ++j) {
        const float* vb = kv + (size_t)(b * TT + j) * 2048 + 1024 + h * HD;
        a1 += s[j] * vb[lane];
        a2 += s[j] * vb[lane + 64];
    }
    attn_out[b * CC + h * HD + lane] = a1 * inv;
    attn_out[b * CC + h * HD + lane + 64] = a2 * inv;
}

// ---------------------------------------------------------------------------
// K5: y = h_current + out[b][c] broadcast over spatial dims
// ---------------------------------------------------------------------------
__global__ __launch_bounds__(256) void final_add(
    const float* __restrict__ hc,
    const float* __restrict__ out,      // [B][C]
    float* __restrict__ y, int n4)
{
    int i = blockIdx.x * blockDim.x + threadIdx.x;
    const int stride = gridDim.x * blockDim.x;
    for (; i < n4; i += stride) {
        float4 v = ((const float4*)hc)[i];
        const float add = out[i / 144];       // 144 float4 per channel
        v.x += add; v.y += add; v.z += add; v.w += add;
        ((float4*)y)[i] = v;
    }
}

// ---------------------------------------------------------------------------
extern "C" void kernel_launch(void* const* d_in, const int* in_sizes, int n_in,
                              void* d_out, int out_size, void* d_ws, size_t ws_size,
                              hipStream_t stream) {
    const float* h_current = (const float*)d_in[0];  // [32,1024,18,32]
    const float* h_buffer  = (const float*)d_in[1];  // [8,32,1024,18,32]
    const float* W_qkv     = (const float*)d_in[2];  // [3072,1024]
    const float* W_out     = (const float*)d_in[3];  // [1024,1024]
    const float* b_out     = (const float*)d_in[4];  // [1024]
    const float* rel_emb   = (const float*)d_in[5];  // [17,8]

    float* ws = (float*)d_ws;
    float* ctx  = ws;                        // [288][1024]  = 294912
    float* kvb  = ws + 294912;               // [288][2048]  = 589824
    float* qb   = ws + 884736;               // [32][1024]
    float* attn = ws + 917504;               // [32][1024]
    float* outp = ws + 950272;               // [32][1024]
    float* part = ws + 983040;               // up to 8*589824 = 4718592

    // K1: pooling (buffer rows first, current rows last -> L3-hot)
    pool_kernel<<<(BB * TT * CC) / 4, 256, 0, stream>>>(h_buffer, h_current, ctx);

    // K2a: KV = ctx @ W_kv^T  (M=288, N=2048), split-K 8
    gemm_splitk<<<dim3((288 / GBM) * (2048 / GBN), NSPLIT), 256, 0, stream>>>(
        ctx, CC, W_qkv + (size_t)1024 * 1024, 1024, part, 2048, 288 * 2048, 2048 / GBN);
    reduce_splitk<<<(288 * 2048 / 4 + 255) / 256, 256, 0, stream>>>(
        part, nullptr, kvb, 288 * 2048, 2047);

    // K2b: Q_last = ctx[:,8,:] @ W_q^T  (M=32, N=1024), split-K 8
    gemm_splitk<<<dim3((32 / GBM) * (1024 / GBN), NSPLIT), 256, 0, stream>>>(
        ctx + 8 * CC, TT * CC, W_qkv, 1024, part, 1024, 32 * 1024, 1024 / GBN);
    reduce_splitk<<<(32 * 1024 / 4 + 255) / 256, 256, 0, stream>>>(
        part, nullptr, qb, 32 * 1024, 1023);

    // K3: attention
    attn_kernel<<<(BB * NH) / 4, 256, 0, stream>>>(kvb, qb, rel_emb, attn);

    // K4: out = attn @ W_out^T + b_out  (M=32, N=1024), split-K 8
    gemm_splitk<<<dim3((32 / GBM) * (1024 / GBN), NSPLIT), 256, 0, stream>>>(
        attn, CC, W_out, 1024, part, 1024, 32 * 1024, 1024 / GBN);
    reduce_splitk<<<(32 * 1024 / 4 + 255) / 256, 256, 0, stream>>>(
        part, b_out, outp, 32 * 1024, 1023);

    // K5: y = h_current + out broadcast
    const int n4 = (BB * CC * HWSZ) / 4;
    final_add<<<2048, 256, 0, stream>>>(h_current, outp, (float*)d_out, n4);
}

// Round 3
// 197.875 us; speedup vs baseline: 1.7594x; 1.0740x over previous
//
#include <hip/hip_runtime.h>
#include <hip/hip_bf16.h>

// Shapes (fixed by the reference)
#define BB 32          // batch
#define CC 1024        // channels
#define HWSZ 576       // H*W
#define KCTX 8         // CONTEXT_LEN
#define TT 9           // K+1
#define NH 8
#define HD 128

#define GBM 32
#define GBN 128
#define GBK 32

#define NS_KV 4        // split-K for KV gemm  (SKLEN 256)
#define NS_Q  8        // split-K for Q gemm   (SKLEN 128)
#define NS_O  32       // split-K for out gemm (SKLEN 32)

#define KV_MN (288 * 2048)   // per-slab elements, KV partials
#define Q_MN  (32 * 1024)
#define O_MN  (32 * 1024)

// ---------------------------------------------------------------------------
// K1: spatial mean pooling -> context [B][T][C]
// Buffer rows in memory order first (streams 604 MB); h_current rows LAST so
// its 75.5 MB is L3-hot for the final kernel's re-read.
// ---------------------------------------------------------------------------
__global__ __launch_bounds__(256) void pool_kernel(
    const float* __restrict__ hbuf,   // [K][B][C][H][W]
    const float* __restrict__ hcur,   // [B][C][H][W]
    float* __restrict__ ctx)          // [B][T][C]
{
    const int wave = threadIdx.x >> 6;
    const int lane = threadIdx.x & 63;
    const int r = blockIdx.x * 4 + wave;          // 0 .. 294911

    const float* src;
    int cidx;
    if (r < KCTX * BB * CC) {
        src = hbuf + (size_t)r * HWSZ;
        const int t = r >> 15;
        const int b = (r >> 10) & 31;
        const int c = r & (CC - 1);
        cidx = (b * TT + t) * CC + c;
    } else {
        const int rc = r - KCTX * BB * CC;
        src = hcur + (size_t)rc * HWSZ;
        const int b = rc >> 10;
        const int c = rc & (CC - 1);
        cidx = (b * TT + KCTX) * CC + c;
    }

    const float4* s4 = (const float4*)src;        // 144 float4 per row
    float4 v0 = s4[lane];
    float4 v1 = s4[lane + 64];
    float sum = v0.x + v0.y + v0.z + v0.w + v1.x + v1.y + v1.z + v1.w;
    if (lane < 16) {
        float4 v2 = s4[lane + 128];
        sum += v2.x + v2.y + v2.z + v2.w;
    }
#pragma unroll
    for (int off = 32; off; off >>= 1) sum += __shfl_xor(sum, off);
    if (lane == 0) ctx[cidx] = sum * (1.0f / 576.0f);
}

// ---------------------------------------------------------------------------
// Shared GEMM tile body: Y[0:32][0:128] (tile origin pre-offset) over one
// K slice [k0, k0+klen). A row-major [32][lda], B row-major [128][ldb].
// ---------------------------------------------------------------------------
__device__ __forceinline__ void gemm_tile_body(
    const float* __restrict__ Ablk, int lda,
    const float* __restrict__ Bblk, int ldb,
    float* __restrict__ Yout, int ldy,
    int k0, int klen,
    float (*As)[GBK + 4], float (*Bs)[GBN + 4])
{
    const int tid = threadIdx.x;
    const int tx = tid & 15;
    const int ty = tid >> 4;

    float acc0[8], acc1[8];
#pragma unroll
    for (int i = 0; i < 8; ++i) { acc0[i] = 0.f; acc1[i] = 0.f; }

    for (int kt = k0; kt < k0 + klen; kt += GBK) {
        {
            const int row = tid >> 3;
            const int kc = (tid & 7) << 2;
            float4 a = *(const float4*)(Ablk + (size_t)row * lda + kt + kc);
            *(float4*)(&As[row][kc]) = a;
        }
        {
            const int kc = (tid & 7) << 2;
            const int r0 = tid >> 3;
#pragma unroll
            for (int rr = 0; rr < 4; ++rr) {
                const int row = r0 + rr * 32;
                float4 bv = *(const float4*)(Bblk + (size_t)row * ldb + kt + kc);
                Bs[kc + 0][row] = bv.x;
                Bs[kc + 1][row] = bv.y;
                Bs[kc + 2][row] = bv.z;
                Bs[kc + 3][row] = bv.w;
            }
        }
        __syncthreads();

#pragma unroll
        for (int k4 = 0; k4 < GBK; k4 += 4) {
            float4 a0 = *(const float4*)(&As[ty * 2 + 0][k4]);
            float4 a1 = *(const float4*)(&As[ty * 2 + 1][k4]);
            const float a0v[4] = {a0.x, a0.y, a0.z, a0.w};
            const float a1v[4] = {a1.x, a1.y, a1.z, a1.w};
#pragma unroll
            for (int i = 0; i < 4; ++i) {
                float4 blo = *(const float4*)(&Bs[k4 + i][tx * 8]);
                float4 bhi = *(const float4*)(&Bs[k4 + i][tx * 8 + 4]);
                acc0[0] += a0v[i] * blo.x;  acc0[1] += a0v[i] * blo.y;
                acc0[2] += a0v[i] * blo.z;  acc0[3] += a0v[i] * blo.w;
                acc0[4] += a0v[i] * bhi.x;  acc0[5] += a0v[i] * bhi.y;
                acc0[6] += a0v[i] * bhi.z;  acc0[7] += a0v[i] * bhi.w;
                acc1[0] += a1v[i] * blo.x;  acc1[1] += a1v[i] * blo.y;
                acc1[2] += a1v[i] * blo.z;  acc1[3] += a1v[i] * blo.w;
                acc1[4] += a1v[i] * bhi.x;  acc1[5] += a1v[i] * bhi.y;
                acc1[6] += a1v[i] * bhi.z;  acc1[7] += a1v[i] * bhi.w;
            }
        }
        __syncthreads();
    }

    const int col = tx * 8;
    const int row0 = ty * 2;
    float* y0 = Yout + (size_t)row0 * ldy + col;
    float* y1 = y0 + ldy;
    *(float4*)(y0 + 0) = make_float4(acc0[0], acc0[1], acc0[2], acc0[3]);
    *(float4*)(y0 + 4) = make_float4(acc0[4], acc0[5], acc0[6], acc0[7]);
    *(float4*)(y1 + 0) = make_float4(acc1[0], acc1[1], acc1[2], acc1[3]);
    *(float4*)(y1 + 4) = make_float4(acc1[4], acc1[5], acc1[6], acc1[7]);
}

// ---------------------------------------------------------------------------
// K2: Q (64 blocks) + KV (576 blocks) projections in ONE launch.
//   Q:  [32 x 1024]  = ctx[:,8,:] @ W_qkv[0:1024]^T       split-K 8
//   KV: [288 x 2048] = ctx @ W_qkv[1024:3072]^T           split-K 4
// ---------------------------------------------------------------------------
__global__ __launch_bounds__(256) void qkv_gemm(
    const float* __restrict__ ctx, const float* __restrict__ Wqkv,
    float* __restrict__ qpart, float* __restrict__ kvpart)
{
    __shared__ float As[GBM][GBK + 4];
    __shared__ float Bs[GBK][GBN + 4];

    const int bid = blockIdx.x;
    if (bid < NS_Q * 8) {
        const int s = bid & (NS_Q - 1);
        const int bn = bid >> 3;
        gemm_tile_body(ctx + 8 * CC, TT * CC,
                       Wqkv + (size_t)bn * GBN * CC, CC,
                       qpart + (size_t)s * Q_MN + bn * GBN, 1024,
                       s * (1024 / NS_Q), 1024 / NS_Q, As, Bs);
    } else {
        const int rel = bid - NS_Q * 8;
        const int s = rel & (NS_KV - 1);
        const int tile = rel >> 2;            // 0..143
        const int bm = tile >> 4;             // 0..8
        const int bn = tile & 15;             // 0..15
        gemm_tile_body(ctx + (size_t)bm * GBM * CC, CC,
                       Wqkv + (size_t)CC * CC + (size_t)bn * GBN * CC, CC,
                       kvpart + (size_t)s * KV_MN + (size_t)bm * GBM * 2048 + bn * GBN, 2048,
                       s * (1024 / NS_KV), 1024 / NS_KV, As, Bs);
    }
}

// ---------------------------------------------------------------------------
// K3: attention, last query only. Sums split-K partials of q and kv inline.
// One wave per (b, h).
// ---------------------------------------------------------------------------
__global__ __launch_bounds__(256) void attn_kernel(
    const float* __restrict__ kvpart,   // NS_KV slabs of [288][2048]
    const float* __restrict__ qpart,    // NS_Q slabs of [32][1024]
    const float* __restrict__ rel_emb,  // [17][8]
    float* __restrict__ attn_out)       // [B][C]
{
    const int wave = threadIdx.x >> 6;
    const int lane = threadIdx.x & 63;
    const int pair = blockIdx.x * 4 + wave;   // 0..255
    const int b = pair >> 3;
    const int h = pair & 7;
    const float scale = 0.08838834764831845f; // 1/sqrt(128)

    const int qoff = b * CC + h * HD;
    float q1 = 0.f, q2 = 0.f;
#pragma unroll
    for (int s = 0; s < NS_Q; ++s) {
        q1 += qpart[(size_t)s * Q_MN + qoff + lane];
        q2 += qpart[(size_t)s * Q_MN + qoff + lane + 64];
    }
    q1 *= scale; q2 *= scale;

    float sc[TT];
#pragma unroll
    for (int j = 0; j < TT; ++j) {
        const size_t base = (size_t)(b * TT + j) * 2048 + h * HD;
        float k1 = 0.f, k2 = 0.f;
#pragma unroll
        for (int s = 0; s < NS_KV; ++s) {
            k1 += kvpart[(size_t)s * KV_MN + base + lane];
            k2 += kvpart[(size_t)s * KV_MN + base + lane + 64];
        }
        float p = q1 * k1 + q2 * k2;
#pragma unroll
        for (int off = 32; off; off >>= 1) p += __shfl_xor(p, off);
        sc[j] = p + rel_emb[(2 * KCTX - j) * NH + h];
    }
    float m = sc[0];
#pragma unroll
    for (int j = 1; j < TT; ++j) m = fmaxf(m, sc[j]);
    float sum = 0.f;
#pragma unroll
    for (int j = 0; j < TT; ++j) { sc[j] = expf(sc[j] - m); sum += sc[j]; }
    const float inv = 1.0f / sum;

    float a1 = 0.f, a2 = 0.f;
#pragma unroll
    for (int j = 0; j < TT; ++j) {
        const size_t base = (size_t)(b * TT + j) * 2048 + 1024 + h * HD;
        float v1 = 0.f, v2 = 0.f;
#pragma unroll
        for (int s = 0; s < NS_KV; ++s) {
            v1 += kvpart[(size_t)s * KV_MN + base + lane];
            v2 += kvpart[(size_t)s * KV_MN + base + lane + 64];
        }
        a1 += sc[j] * v1;
        a2 += sc[j] * v2;
    }
    attn_out[qoff + lane] = a1 * inv;
    attn_out[qoff + lane + 64] = a2 * inv;
}

// ---------------------------------------------------------------------------
// K4: out projection, split-K 32 (one k-step per block, 256 blocks)
// ---------------------------------------------------------------------------
__global__ __launch_bounds__(256) void out_gemm(
    const float* __restrict__ attnb, const float* __restrict__ Wout,
    float* __restrict__ outpart)
{
    __shared__ float As[GBM][GBK + 4];
    __shared__ float Bs[GBK][GBN + 4];
    const int s = blockIdx.x & (NS_O - 1);
    const int bn = blockIdx.x >> 5;
    gemm_tile_body(attnb, 1024,
                   Wout + (size_t)bn * GBN * CC, CC,
                   outpart + (size_t)s * O_MN + bn * GBN, 1024,
                   s * (1024 / NS_O), 1024 / NS_O, As, Bs);
}

// ---------------------------------------------------------------------------
// K5: y = h_current + (sum of 32 out-partials + bias) broadcast per channel.
// One wave per channel (same access shape as pool's h_current pass).
// ---------------------------------------------------------------------------
__global__ __launch_bounds__(256) void final_bcast(
    const float* __restrict__ hc,
    const float* __restrict__ outpart,  // NS_O slabs of [32][1024]
    const float* __restrict__ bias,     // [1024]
    float* __restrict__ y)
{
    const int wave = threadIdx.x >> 6;
    const int lane = threadIdx.x & 63;
    const int r = blockIdx.x * 4 + wave;          // channel-row 0..32767
    const int c = r & (CC - 1);

    float p = outpart[(size_t)(lane & 31) * O_MN + r];
#pragma unroll
    for (int off = 16; off; off >>= 1) p += __shfl_xor(p, off);
    const float add = p + bias[c];

    const float4* s4 = (const float4*)(hc + (size_t)r * HWSZ);
    float4* d4 = (float4*)(y + (size_t)r * HWSZ);
    float4 v0 = s4[lane];
    v0.x += add; v0.y += add; v0.z += add; v0.w += add;
    d4[lane] = v0;
    float4 v1 = s4[lane + 64];
    v1.x += add; v1.y += add; v1.z += add; v1.w += add;
    d4[lane + 64] = v1;
    if (lane < 16) {
        float4 v2 = s4[lane + 128];
        v2.x += add; v2.y += add; v2.z += add; v2.w += add;
        d4[lane + 128] = v2;
    }
}

// ---------------------------------------------------------------------------
extern "C" void kernel_launch(void* const* d_in, const int* in_sizes, int n_in,
                              void* d_out, int out_size, void* d_ws, size_t ws_size,
                              hipStream_t stream) {
    const float* h_current = (const float*)d_in[0];  // [32,1024,18,32]
    const float* h_buffer  = (const float*)d_in[1];  // [8,32,1024,18,32]
    const float* W_qkv     = (const float*)d_in[2];  // [3072,1024]
    const float* W_out     = (const float*)d_in[3];  // [1024,1024]
    const float* b_out     = (const float*)d_in[4];  // [1024]
    const float* rel_emb   = (const float*)d_in[5];  // [17,8]

    float* ws = (float*)d_ws;
    float* ctx     = ws;                                   // 294912
    float* kvpart  = ctx + 294912;                         // 4 * 589824 = 2359296
    float* qpart   = kvpart + (size_t)NS_KV * KV_MN;       // 8 * 32768  = 262144
    float* attnb   = qpart + (size_t)NS_Q * Q_MN;          // 32768
    float* outpart = attnb + 32768;                        // 32 * 32768 = 1048576
    // total 3,997,696 floats = 16.0 MB

    // K1: pooling (buffer rows first, current rows last -> L3-hot)
    pool_kernel<<<(BB * TT * CC) / 4, 256, 0, stream>>>(h_buffer, h_current, ctx);

    // K2: Q + KV projections, one launch (640 blocks)
    qkv_gemm<<<NS_Q * 8 + NS_KV * 144, 256, 0, stream>>>(ctx, W_qkv, qpart, kvpart);

    // K3: attention (sums split-K partials inline)
    attn_kernel<<<(BB * NH) / 4, 256, 0, stream>>>(kvpart, qpart, rel_emb, attnb);

    // K4: out projection (256 blocks, 1 k-step each)
    out_gemm<<<8 * NS_O, 256, 0, stream>>>(attnb, W_out, outpart);

    // K5: broadcast-add (sums out partials + bias inline)
    final_bcast<<<(BB * CC) / 4, 256, 0, stream>>>(h_current, outpart, b_out, (float*)d_out);
}

// Round 4
// 179.700 us; speedup vs baseline: 1.9373x; 1.1011x over previous
//
#include <hip/hip_runtime.h>
#include <hip/hip_bf16.h>

// Shapes (fixed by the reference)
#define BB 32          // batch
#define CC 1024        // channels
#define HWSZ 576       // H*W
#define KCTX 8         // CONTEXT_LEN
#define TT 9           // K+1
#define NH 8
#define HD 128

#define GBM 32
#define GBN 128
#define GBK 32

#define NS_KV 4        // split-K for KV gemm  (SKLEN 256)
#define NS_Q  8        // split-K for Q gemm   (SKLEN 128)
#define NS_O  32       // split-K for out gemm (SKLEN 32)

#define KV_MN (288 * 2048)
#define Q_MN  (32 * 1024)

typedef float v4f __attribute__((ext_vector_type(4)));

// ---------------------------------------------------------------------------
// K1: spatial mean pooling -> context [B][T][C].  Grid-stride over rows.
// Buffer rows (memory order, NT loads: no L3 pollution) first; h_current rows
// last with normal loads so they stay L3-resident for the final kernel.
// ---------------------------------------------------------------------------
__global__ __launch_bounds__(256) void pool_kernel(
    const float* __restrict__ hbuf,   // [K][B][C][H][W]
    const float* __restrict__ hcur,   // [B][C][H][W]
    float* __restrict__ ctx)          // [B][T][C]
{
    const int wave = threadIdx.x >> 6;
    const int lane = threadIdx.x & 63;
    const int stride = gridDim.x * 4;
    const int nrows = BB * TT * CC;

    for (int r = blockIdx.x * 4 + wave; r < nrows; r += stride) {
        float sum;
        int cidx;
        if (r < KCTX * BB * CC) {                 // buffer rows, memory order
            const v4f* s4 = (const v4f*)(hbuf + (size_t)r * HWSZ);
            const int t = r >> 15;
            const int b = (r >> 10) & 31;
            const int c = r & (CC - 1);
            cidx = (b * TT + t) * CC + c;
            v4f v0 = __builtin_nontemporal_load(s4 + lane);
            v4f v1 = __builtin_nontemporal_load(s4 + lane + 64);
            sum = v0.x + v0.y + v0.z + v0.w + v1.x + v1.y + v1.z + v1.w;
            if (lane < 16) {
                v4f v2 = __builtin_nontemporal_load(s4 + lane + 128);
                sum += v2.x + v2.y + v2.z + v2.w;
            }
        } else {                                  // current rows, last, cached
            const int rc = r - KCTX * BB * CC;
            const v4f* s4 = (const v4f*)(hcur + (size_t)rc * HWSZ);
            const int b = rc >> 10;
            const int c = rc & (CC - 1);
            cidx = (b * TT + KCTX) * CC + c;
            v4f v0 = s4[lane];
            v4f v1 = s4[lane + 64];
            sum = v0.x + v0.y + v0.z + v0.w + v1.x + v1.y + v1.z + v1.w;
            if (lane < 16) {
                v4f v2 = s4[lane + 128];
                sum += v2.x + v2.y + v2.z + v2.w;
            }
        }
#pragma unroll
        for (int off = 32; off; off >>= 1) sum += __shfl_xor(sum, off);
        if (lane == 0) ctx[cidx] = sum * (1.0f / 576.0f);
    }
}

// ---------------------------------------------------------------------------
// Shared GEMM tile body. ES = output element stride (1: float4 stores;
// 32: scalar strided stores for the [row][slab] partial layout).
// ---------------------------------------------------------------------------
template <int ES>
__device__ __forceinline__ void gemm_tile_body(
    const float* __restrict__ Ablk, int lda,
    const float* __restrict__ Bblk, int ldb,
    float* __restrict__ Yout, int ldy,
    int k0, int klen,
    float (*As)[GBK + 4], float (*Bs)[GBN + 4])
{
    const int tid = threadIdx.x;
    const int tx = tid & 15;
    const int ty = tid >> 4;

    float acc0[8], acc1[8];
#pragma unroll
    for (int i = 0; i < 8; ++i) { acc0[i] = 0.f; acc1[i] = 0.f; }

    for (int kt = k0; kt < k0 + klen; kt += GBK) {
        {
            const int row = tid >> 3;
            const int kc = (tid & 7) << 2;
            float4 a = *(const float4*)(Ablk + (size_t)row * lda + kt + kc);
            *(float4*)(&As[row][kc]) = a;
        }
        {
            const int kc = (tid & 7) << 2;
            const int r0 = tid >> 3;
#pragma unroll
            for (int rr = 0; rr < 4; ++rr) {
                const int row = r0 + rr * 32;
                float4 bv = *(const float4*)(Bblk + (size_t)row * ldb + kt + kc);
                Bs[kc + 0][row] = bv.x;
                Bs[kc + 1][row] = bv.y;
                Bs[kc + 2][row] = bv.z;
                Bs[kc + 3][row] = bv.w;
            }
        }
        __syncthreads();

#pragma unroll
        for (int k4 = 0; k4 < GBK; k4 += 4) {
            float4 a0 = *(const float4*)(&As[ty * 2 + 0][k4]);
            float4 a1 = *(const float4*)(&As[ty * 2 + 1][k4]);
            const float a0v[4] = {a0.x, a0.y, a0.z, a0.w};
            const float a1v[4] = {a1.x, a1.y, a1.z, a1.w};
#pragma unroll
            for (int i = 0; i < 4; ++i) {
                float4 blo = *(const float4*)(&Bs[k4 + i][tx * 8]);
                float4 bhi = *(const float4*)(&Bs[k4 + i][tx * 8 + 4]);
                acc0[0] += a0v[i] * blo.x;  acc0[1] += a0v[i] * blo.y;
                acc0[2] += a0v[i] * blo.z;  acc0[3] += a0v[i] * blo.w;
                acc0[4] += a0v[i] * bhi.x;  acc0[5] += a0v[i] * bhi.y;
                acc0[6] += a0v[i] * bhi.z;  acc0[7] += a0v[i] * bhi.w;
                acc1[0] += a1v[i] * blo.x;  acc1[1] += a1v[i] * blo.y;
                acc1[2] += a1v[i] * blo.z;  acc1[3] += a1v[i] * blo.w;
                acc1[4] += a1v[i] * bhi.x;  acc1[5] += a1v[i] * bhi.y;
                acc1[6] += a1v[i] * bhi.z;  acc1[7] += a1v[i] * bhi.w;
            }
        }
        __syncthreads();
    }

    const int col = tx * 8;
    const int row0 = ty * 2;
    if (ES == 1) {
        float* y0 = Yout + (size_t)row0 * ldy + col;
        float* y1 = y0 + ldy;
        *(float4*)(y0 + 0) = make_float4(acc0[0], acc0[1], acc0[2], acc0[3]);
        *(float4*)(y0 + 4) = make_float4(acc0[4], acc0[5], acc0[6], acc0[7]);
        *(float4*)(y1 + 0) = make_float4(acc1[0], acc1[1], acc1[2], acc1[3]);
        *(float4*)(y1 + 4) = make_float4(acc1[4], acc1[5], acc1[6], acc1[7]);
    } else {
        float* y0 = Yout + (size_t)row0 * ldy;
        float* y1 = y0 + ldy;
#pragma unroll
        for (int i = 0; i < 8; ++i) {
            y0[(size_t)(col + i) * ES] = acc0[i];
            y1[(size_t)(col + i) * ES] = acc1[i];
        }
    }
}

// ---------------------------------------------------------------------------
// K2: Q (64 blocks) + KV (576 blocks) projections in ONE launch.
// ---------------------------------------------------------------------------
__global__ __launch_bounds__(256) void qkv_gemm(
    const float* __restrict__ ctx, const float* __restrict__ Wqkv,
    float* __restrict__ qpart, float* __restrict__ kvpart)
{
    __shared__ float As[GBM][GBK + 4];
    __shared__ float Bs[GBK][GBN + 4];

    const int bid = blockIdx.x;
    if (bid < NS_Q * 8) {
        const int s = bid & (NS_Q - 1);
        const int bn = bid >> 3;
        gemm_tile_body<1>(ctx + 8 * CC, TT * CC,
                          Wqkv + (size_t)bn * GBN * CC, CC,
                          qpart + (size_t)s * Q_MN + bn * GBN, 1024,
                          s * (1024 / NS_Q), 1024 / NS_Q, As, Bs);
    } else {
        const int rel = bid - NS_Q * 8;
        const int s = rel & (NS_KV - 1);
        const int tile = rel >> 2;            // 0..143
        const int bm = tile >> 4;             // 0..8
        const int bn = tile & 15;             // 0..15
        gemm_tile_body<1>(ctx + (size_t)bm * GBM * CC, CC,
                          Wqkv + (size_t)CC * CC + (size_t)bn * GBN * CC, CC,
                          kvpart + (size_t)s * KV_MN + (size_t)bm * GBM * 2048 + bn * GBN, 2048,
                          s * (1024 / NS_KV), 1024 / NS_KV, As, Bs);
    }
}

// ---------------------------------------------------------------------------
// K3: attention, last query only. One wave per block, 256 blocks.
// ---------------------------------------------------------------------------
__global__ __launch_bounds__(64) void attn_kernel(
    const float* __restrict__ kvpart,   // NS_KV slabs of [288][2048]
    const float* __restrict__ qpart,    // NS_Q slabs of [32][1024]
    const float* __restrict__ rel_emb,  // [17][8]
    float* __restrict__ attn_out)       // [B][C]
{
    const int lane = threadIdx.x;
    const int pair = blockIdx.x;              // 0..255
    const int b = pair >> 3;
    const int h = pair & 7;
    const float scale = 0.08838834764831845f; // 1/sqrt(128)

    const int qoff = b * CC + h * HD;
    float q1 = 0.f, q2 = 0.f;
#pragma unroll
    for (int s = 0; s < NS_Q; ++s) {
        q1 += qpart[(size_t)s * Q_MN + qoff + lane];
        q2 += qpart[(size_t)s * Q_MN + qoff + lane + 64];
    }
    q1 *= scale; q2 *= scale;

    float sc[TT];
#pragma unroll
    for (int j = 0; j < TT; ++j) {
        const size_t base = (size_t)(b * TT + j) * 2048 + h * HD;
        float k1 = 0.f, k2 = 0.f;
#pragma unroll
        for (int s = 0; s < NS_KV; ++s) {
            k1 += kvpart[(size_t)s * KV_MN + base + lane];
            k2 += kvpart[(size_t)s * KV_MN + base + lane + 64];
        }
        float p = q1 * k1 + q2 * k2;
#pragma unroll
        for (int off = 32; off; off >>= 1) p += __shfl_xor(p, off);
        sc[j] = p + rel_emb[(2 * KCTX - j) * NH + h];
    }
    float m = sc[0];
#pragma unroll
    for (int j = 1; j < TT; ++j) m = fmaxf(m, sc[j]);
    float sum = 0.f;
#pragma unroll
    for (int j = 0; j < TT; ++j) { sc[j] = expf(sc[j] - m); sum += sc[j]; }
    const float inv = 1.0f / sum;

    float a1 = 0.f, a2 = 0.f;
#pragma unroll
    for (int j = 0; j < TT; ++j) {
        const size_t base = (size_t)(b * TT + j) * 2048 + 1024 + h * HD;
        float v1 = 0.f, v2 = 0.f;
#pragma unroll
        for (int s = 0; s < NS_KV; ++s) {
            v1 += kvpart[(size_t)s * KV_MN + base + lane];
            v2 += kvpart[(size_t)s * KV_MN + base + lane + 64];
        }
        a1 += sc[j] * v1;
        a2 += sc[j] * v2;
    }
    attn_out[qoff + lane] = a1 * inv;
    attn_out[qoff + lane + 64] = a2 * inv;
}

// ---------------------------------------------------------------------------
// K4: out projection, split-K 32. Partials in [row*1024+col][32] layout so
// the final kernel reduces 32 CONTIGUOUS floats per output element.
// ---------------------------------------------------------------------------
__global__ __launch_bounds__(256) void out_gemm(
    const float* __restrict__ attnb, const float* __restrict__ Wout,
    float* __restrict__ outpart)       // [32*1024][32]
{
    __shared__ float As[GBM][GBK + 4];
    __shared__ float Bs[GBK][GBN + 4];
    const int s = blockIdx.x & (NS_O - 1);
    const int bn = blockIdx.x >> 5;
    gemm_tile_body<NS_O>(attnb, 1024,
                         Wout + (size_t)bn * GBN * CC, CC,
                         outpart + (size_t)bn * GBN * NS_O + s, 1024 * NS_O,
                         s * (1024 / NS_O), 1024 / NS_O, As, Bs);
}

// ---------------------------------------------------------------------------
// K5: y = h_current + (sum of outpart[r][0:32] + bias[c]).  Grid-stride.
// ---------------------------------------------------------------------------
__global__ __launch_bounds__(256) void final_bcast(
    const float* __restrict__ hc,
    const float* __restrict__ outpart,  // [32768][32]
    const float* __restrict__ bias,     // [1024]
    float* __restrict__ y)
{
    const int wave = threadIdx.x >> 6;
    const int lane = threadIdx.x & 63;
    const int stride = gridDim.x * 4;
    const int nrows = BB * CC;

    for (int r = blockIdx.x * 4 + wave; r < nrows; r += stride) {
        const int c = r & (CC - 1);
        // 32 contiguous partials: lanes 0-7 cover them (dup x8 across wave)
        v4f p4 = *((const v4f*)(outpart + (size_t)r * NS_O) + (lane & 7));
        float p = p4.x + p4.y + p4.z + p4.w;
        p += __shfl_xor(p, 1);
        p += __shfl_xor(p, 2);
        p += __shfl_xor(p, 4);
        const float add = p + bias[c];

        const v4f* s4 = (const v4f*)(hc + (size_t)r * HWSZ);
        v4f* d4 = (v4f*)(y + (size_t)r * HWSZ);
        v4f v0 = s4[lane];
        v0.x += add; v0.y += add; v0.z += add; v0.w += add;
        __builtin_nontemporal_store(v0, d4 + lane);
        v4f v1 = s4[lane + 64];
        v1.x += add; v1.y += add; v1.z += add; v1.w += add;
        __builtin_nontemporal_store(v1, d4 + lane + 64);
        if (lane < 16) {
            v4f v2 = s4[lane + 128];
            v2.x += add; v2.y += add; v2.z += add; v2.w += add;
            __builtin_nontemporal_store(v2, d4 + lane + 128);
        }
    }
}

// ---------------------------------------------------------------------------
extern "C" void kernel_launch(void* const* d_in, const int* in_sizes, int n_in,
                              void* d_out, int out_size, void* d_ws, size_t ws_size,
                              hipStream_t stream) {
    const float* h_current = (const float*)d_in[0];  // [32,1024,18,32]
    const float* h_buffer  = (const float*)d_in[1];  // [8,32,1024,18,32]
    const float* W_qkv     = (const float*)d_in[2];  // [3072,1024]
    const float* W_out     = (const float*)d_in[3];  // [1024,1024]
    const float* b_out     = (const float*)d_in[4];  // [1024]
    const float* rel_emb   = (const float*)d_in[5];  // [17,8]

    float* ws = (float*)d_ws;
    float* ctx     = ws;                                   // 294912
    float* kvpart  = ctx + 294912;                         // 4 * 589824
    float* qpart   = kvpart + (size_t)NS_KV * KV_MN;       // 8 * 32768
    float* attnb   = qpart + (size_t)NS_Q * Q_MN;          // 32768
    float* outpart = attnb + 32768;                        // 32768 * 32
    // total ~16.0 MB

    // K1: pooling (grid-stride; buffer rows NT-first, current rows last)
    pool_kernel<<<2048, 256, 0, stream>>>(h_buffer, h_current, ctx);

    // K2: Q + KV projections (640 blocks)
    qkv_gemm<<<NS_Q * 8 + NS_KV * 144, 256, 0, stream>>>(ctx, W_qkv, qpart, kvpart);

    // K3: attention (256 single-wave blocks)
    attn_kernel<<<BB * NH, 64, 0, stream>>>(kvpart, qpart, rel_emb, attnb);

    // K4: out projection (256 blocks, [row][slab] partial layout)
    out_gemm<<<8 * NS_O, 256, 0, stream>>>(attnb, W_out, outpart);

    // K5: broadcast-add (grid-stride, contiguous partial reduce)
    final_bcast<<<2048, 256, 0, stream>>>(h_current, outpart, b_out, (float*)d_out);
}

// Round 5
// 165.128 us; speedup vs baseline: 2.1083x; 1.0882x over previous
//
#include <hip/hip_runtime.h>
#include <hip/hip_bf16.h>

// Shapes (fixed by the reference)
#define BB 32          // batch
#define CC 1024        // channels
#define HWSZ 576       // H*W
#define KCTX 8         // CONTEXT_LEN
#define TT 9           // K+1
#define NH 8
#define HD 128

#define GBM 32
#define GBN 128
#define GBK 32

#define NS_KV 8        // split-K for KV gemm (SKLEN 128)
#define NS_Q  8        // split-K for Q gemm  (SKLEN 128)

#define KV_MN (288 * 2048)
#define Q_MN  (32 * 1024)

typedef float v4f __attribute__((ext_vector_type(4)));

// ---------------------------------------------------------------------------
// K1: spatial mean pooling -> context [B][T][C].
// 16 lanes per row, 4 rows per wave: each lane streams 9 float4 (high MLP,
// no tail divergence). Buffer rows (memory order, NT loads) first; h_current
// rows last with cached loads so they stay L3-resident for the final kernel.
// ---------------------------------------------------------------------------
__global__ __launch_bounds__(256) void pool_kernel(
    const float* __restrict__ hbuf,   // [K][B][C][H][W]
    const float* __restrict__ hcur,   // [B][C][H][W]
    float* __restrict__ ctx)          // [B][T][C]
{
    const int wave = threadIdx.x >> 6;
    const int lane = threadIdx.x & 63;
    const int sub  = lane >> 4;        // row-within-wave 0..3
    const int l16  = lane & 15;
    const int stride = gridDim.x * 16; // rows per full sweep
    const int nrows = BB * TT * CC;    // 294912

    for (int r0 = (blockIdx.x * 4 + wave) * 4; r0 < nrows; r0 += stride) {
        const int r = r0 + sub;
        v4f acc = {0.f, 0.f, 0.f, 0.f};
        int cidx;
        if (r < KCTX * BB * CC) {                 // buffer rows, memory order
            const v4f* s4 = (const v4f*)(hbuf + (size_t)r * HWSZ);
            const int t = r >> 15;
            const int b = (r >> 10) & 31;
            cidx = (b * TT + t) * CC + (r & (CC - 1));
#pragma unroll
            for (int j = 0; j < 9; ++j)
                acc += __builtin_nontemporal_load(s4 + l16 + 16 * j);
        } else {                                  // current rows, last, cached
            const int rc = r - KCTX * BB * CC;
            const v4f* s4 = (const v4f*)(hcur + (size_t)rc * HWSZ);
            cidx = ((rc >> 10) * TT + KCTX) * CC + (rc & (CC - 1));
#pragma unroll
            for (int j = 0; j < 9; ++j)
                acc += s4[l16 + 16 * j];
        }
        float sum = acc.x + acc.y + acc.z + acc.w;
        sum += __shfl_xor(sum, 1);
        sum += __shfl_xor(sum, 2);
        sum += __shfl_xor(sum, 4);
        sum += __shfl_xor(sum, 8);
        if (l16 == 0) ctx[cidx] = sum * (1.0f / 576.0f);
    }
}

// ---------------------------------------------------------------------------
// Shared GEMM tile body (32x128 tile, one K slice).
// ---------------------------------------------------------------------------
__device__ __forceinline__ void gemm_tile_body(
    const float* __restrict__ Ablk, int lda,
    const float* __restrict__ Bblk, int ldb,
    float* __restrict__ Yout, int ldy,
    int k0, int klen,
    float (*As)[GBK + 4], float (*Bs)[GBN + 4])
{
    const int tid = threadIdx.x;
    const int tx = tid & 15;
    const int ty = tid >> 4;

    float acc0[8], acc1[8];
#pragma unroll
    for (int i = 0; i < 8; ++i) { acc0[i] = 0.f; acc1[i] = 0.f; }

    for (int kt = k0; kt < k0 + klen; kt += GBK) {
        {
            const int row = tid >> 3;
            const int kc = (tid & 7) << 2;
            float4 a = *(const float4*)(Ablk + (size_t)row * lda + kt + kc);
            *(float4*)(&As[row][kc]) = a;
        }
        {
            const int kc = (tid & 7) << 2;
            const int r0 = tid >> 3;
#pragma unroll
            for (int rr = 0; rr < 4; ++rr) {
                const int row = r0 + rr * 32;
                float4 bv = *(const float4*)(Bblk + (size_t)row * ldb + kt + kc);
                Bs[kc + 0][row] = bv.x;
                Bs[kc + 1][row] = bv.y;
                Bs[kc + 2][row] = bv.z;
                Bs[kc + 3][row] = bv.w;
            }
        }
        __syncthreads();

#pragma unroll
        for (int k4 = 0; k4 < GBK; k4 += 4) {
            float4 a0 = *(const float4*)(&As[ty * 2 + 0][k4]);
            float4 a1 = *(const float4*)(&As[ty * 2 + 1][k4]);
            const float a0v[4] = {a0.x, a0.y, a0.z, a0.w};
            const float a1v[4] = {a1.x, a1.y, a1.z, a1.w};
#pragma unroll
            for (int i = 0; i < 4; ++i) {
                float4 blo = *(const float4*)(&Bs[k4 + i][tx * 8]);
                float4 bhi = *(const float4*)(&Bs[k4 + i][tx * 8 + 4]);
                acc0[0] += a0v[i] * blo.x;  acc0[1] += a0v[i] * blo.y;
                acc0[2] += a0v[i] * blo.z;  acc0[3] += a0v[i] * blo.w;
                acc0[4] += a0v[i] * bhi.x;  acc0[5] += a0v[i] * bhi.y;
                acc0[6] += a0v[i] * bhi.z;  acc0[7] += a0v[i] * bhi.w;
                acc1[0] += a1v[i] * blo.x;  acc1[1] += a1v[i] * blo.y;
                acc1[2] += a1v[i] * blo.z;  acc1[3] += a1v[i] * blo.w;
                acc1[4] += a1v[i] * bhi.x;  acc1[5] += a1v[i] * bhi.y;
                acc1[6] += a1v[i] * bhi.z;  acc1[7] += a1v[i] * bhi.w;
            }
        }
        __syncthreads();
    }

    const int col = tx * 8;
    const int row0 = ty * 2;
    float* y0 = Yout + (size_t)row0 * ldy + col;
    float* y1 = y0 + ldy;
    *(float4*)(y0 + 0) = make_float4(acc0[0], acc0[1], acc0[2], acc0[3]);
    *(float4*)(y0 + 4) = make_float4(acc0[4], acc0[5], acc0[6], acc0[7]);
    *(float4*)(y1 + 0) = make_float4(acc1[0], acc1[1], acc1[2], acc1[3]);
    *(float4*)(y1 + 4) = make_float4(acc1[4], acc1[5], acc1[6], acc1[7]);
}

// ---------------------------------------------------------------------------
// K2: Q (64 blocks) + KV (1152 blocks) projections in ONE launch.
// ---------------------------------------------------------------------------
__global__ __launch_bounds__(256) void qkv_gemm(
    const float* __restrict__ ctx, const float* __restrict__ Wqkv,
    float* __restrict__ qpart, float* __restrict__ kvpart)
{
    __shared__ float As[GBM][GBK + 4];
    __shared__ float Bs[GBK][GBN + 4];

    const int bid = blockIdx.x;
    if (bid < NS_Q * 8) {
        const int s = bid & (NS_Q - 1);
        const int bn = bid >> 3;
        gemm_tile_body(ctx + 8 * CC, TT * CC,
                       Wqkv + (size_t)bn * GBN * CC, CC,
                       qpart + (size_t)s * Q_MN + bn * GBN, 1024,
                       s * (1024 / NS_Q), 1024 / NS_Q, As, Bs);
    } else {
        const int rel = bid - NS_Q * 8;
        const int s = rel & (NS_KV - 1);
        const int tile = rel >> 3;            // 0..143
        const int bm = tile >> 4;             // 0..8
        const int bn = tile & 15;             // 0..15
        gemm_tile_body(ctx + (size_t)bm * GBM * CC, CC,
                       Wqkv + (size_t)CC * CC + (size_t)bn * GBN * CC, CC,
                       kvpart + (size_t)s * KV_MN + (size_t)bm * GBM * 2048 + bn * GBN, 2048,
                       s * (1024 / NS_KV), 1024 / NS_KV, As, Bs);
    }
}

// ---------------------------------------------------------------------------
// K3: attention, last query only. One wave per block, 256 blocks.
// Sums split-K partials of q and kv inline (L2-hot).
// ---------------------------------------------------------------------------
__global__ __launch_bounds__(64) void attn_kernel(
    const float* __restrict__ kvpart,   // NS_KV slabs of [288][2048]
    const float* __restrict__ qpart,    // NS_Q slabs of [32][1024]
    const float* __restrict__ rel_emb,  // [17][8]
    float* __restrict__ attn_out)       // [B][C]
{
    const int lane = threadIdx.x;
    const int pair = blockIdx.x;              // 0..255
    const int b = pair >> 3;
    const int h = pair & 7;
    const float scale = 0.08838834764831845f; // 1/sqrt(128)

    const int qoff = b * CC + h * HD;
    float q1 = 0.f, q2 = 0.f;
#pragma unroll
    for (int s = 0; s < NS_Q; ++s) {
        q1 += qpart[(size_t)s * Q_MN + qoff + lane];
        q2 += qpart[(size_t)s * Q_MN + qoff + lane + 64];
    }
    q1 *= scale; q2 *= scale;

    float sc[TT];
#pragma unroll
    for (int j = 0; j < TT; ++j) {
        const size_t base = (size_t)(b * TT + j) * 2048 + h * HD;
        float k1 = 0.f, k2 = 0.f;
#pragma unroll
        for (int s = 0; s < NS_KV; ++s) {
            k1 += kvpart[(size_t)s * KV_MN + base + lane];
            k2 += kvpart[(size_t)s * KV_MN + base + lane + 64];
        }
        float p = q1 * k1 + q2 * k2;
#pragma unroll
        for (int off = 32; off; off >>= 1) p += __shfl_xor(p, off);
        sc[j] = p + rel_emb[(2 * KCTX - j) * NH + h];
    }
    float m = sc[0];
#pragma unroll
    for (int j = 1; j < TT; ++j) m = fmaxf(m, sc[j]);
    float sum = 0.f;
#pragma unroll
    for (int j = 0; j < TT; ++j) { sc[j] = expf(sc[j] - m); sum += sc[j]; }
    const float inv = 1.0f / sum;

    float a1 = 0.f, a2 = 0.f;
#pragma unroll
    for (int j = 0; j < TT; ++j) {
        const size_t base = (size_t)(b * TT + j) * 2048 + 1024 + h * HD;
        float v1 = 0.f, v2 = 0.f;
#pragma unroll
        for (int s = 0; s < NS_KV; ++s) {
            v1 += kvpart[(size_t)s * KV_MN + base + lane];
            v2 += kvpart[(size_t)s * KV_MN + base + lane + 64];
        }
        a1 += sc[j] * v1;
        a2 += sc[j] * v2;
    }
    attn_out[qoff + lane] = a1 * inv;
    attn_out[qoff + lane + 64] = a2 * inv;
}

// ---------------------------------------------------------------------------
// K4: fused out-projection + broadcast residual add.
// One wave per output row r=(b,c'): dot(attnb[b,:], Wout[c',:]) (attnb and
// Wout are L2-resident: 128 KB + 4 MB), + bias, broadcast-add over 576
// spatial elements streamed from L3-hot h_current, NT store to y.
// ---------------------------------------------------------------------------
__global__ __launch_bounds__(256) void final_fused(
    const float* __restrict__ hc,       // [B][C][H][W]
    const float* __restrict__ attnb,    // [32][1024]
    const float* __restrict__ Wout,     // [1024][1024]
    const float* __restrict__ bias,     // [1024]
    float* __restrict__ y)
{
    const int wave = threadIdx.x >> 6;
    const int lane = threadIdx.x & 63;
    const int stride = gridDim.x * 4;
    const int nrows = BB * CC;

    for (int r = blockIdx.x * 4 + wave; r < nrows; r += stride) {
        const int b = r >> 10;
        const int c = r & (CC - 1);

        // out[b][c] = attnb[b,:] . Wout[c,:]  (64 lanes x 4 float4 each)
        const v4f* ar = (const v4f*)(attnb + (size_t)b * CC);
        const v4f* wr = (const v4f*)(Wout + (size_t)c * CC);
        v4f acc = {0.f, 0.f, 0.f, 0.f};
#pragma unroll
        for (int j = 0; j < 4; ++j) {
            v4f a = ar[lane + 64 * j];
            v4f w = wr[lane + 64 * j];
            acc += a * w;
        }
        float dot = acc.x + acc.y + acc.z + acc.w;
#pragma unroll
        for (int off = 32; off; off >>= 1) dot += __shfl_xor(dot, off);
        const float add = dot + bias[c];

        const v4f* s4 = (const v4f*)(hc + (size_t)r * HWSZ);
        v4f* d4 = (v4f*)(y + (size_t)r * HWSZ);
        v4f v0 = s4[lane];
        v0.x += add; v0.y += add; v0.z += add; v0.w += add;
        __builtin_nontemporal_store(v0, d4 + lane);
        v4f v1 = s4[lane + 64];
        v1.x += add; v1.y += add; v1.z += add; v1.w += add;
        __builtin_nontemporal_store(v1, d4 + lane + 64);
        if (lane < 16) {
            v4f v2 = s4[lane + 128];
            v2.x += add; v2.y += add; v2.z += add; v2.w += add;
            __builtin_nontemporal_store(v2, d4 + lane + 128);
        }
    }
}

// ---------------------------------------------------------------------------
extern "C" void kernel_launch(void* const* d_in, const int* in_sizes, int n_in,
                              void* d_out, int out_size, void* d_ws, size_t ws_size,
                              hipStream_t stream) {
    const float* h_current = (const float*)d_in[0];  // [32,1024,18,32]
    const float* h_buffer  = (const float*)d_in[1];  // [8,32,1024,18,32]
    const float* W_qkv     = (const float*)d_in[2];  // [3072,1024]
    const float* W_out     = (const float*)d_in[3];  // [1024,1024]
    const float* b_out     = (const float*)d_in[4];  // [1024]
    const float* rel_emb   = (const float*)d_in[5];  // [17,8]

    float* ws = (float*)d_ws;
    float* ctx    = ws;                                   // 294912
    float* kvpart = ctx + 294912;                         // 8 * 589824 = 4718592
    float* qpart  = kvpart + (size_t)NS_KV * KV_MN;       // 8 * 32768
    float* attnb  = qpart + (size_t)NS_Q * Q_MN;          // 32768
    // total 5,308,416 floats = 21.2 MB

    // K1: pooling (16 lanes/row, grid-stride; buffer NT-first, current last)
    pool_kernel<<<2048, 256, 0, stream>>>(h_buffer, h_current, ctx);

    // K2: Q + KV projections (1216 blocks)
    qkv_gemm<<<NS_Q * 8 + NS_KV * 144, 256, 0, stream>>>(ctx, W_qkv, qpart, kvpart);

    // K3: attention (256 single-wave blocks)
    attn_kernel<<<BB * NH, 64, 0, stream>>>(kvpart, qpart, rel_emb, attnb);

    // K4: fused out-projection + broadcast residual add
    final_fused<<<2048, 256, 0, stream>>>(h_current, attnb, W_out, b_out, (float*)d_out);
}